// Round 6
// baseline (66.829 us; speedup 1.0000x reference)
//
#include <hip/hip_runtime.h>
#include <stdint.h>

#define IMG_H 512
#define IMG_W 512
#define NB 16
#define NC 8
#define HW (IMG_H * IMG_W)

#define TILE 64
#define HALO 15
#define RROWS (TILE + 2 * HALO)   // 94
#define NTASK (RROWS * 4)         // 376 (row, word) tasks
#define NBLK (NB * 64)            // 1024 tile blocks

typedef float f4 __attribute__((ext_vector_type(4)));

// ---------------------------------------------------------------------------
// Kernel 1: boundary bitmask. boundary(p) = any valid 3x3 neighbor differs.
// One block per row (16*512 blocks, 512 threads). __ballot packs 64 pixels.
// ---------------------------------------------------------------------------
__global__ __launch_bounds__(512) void boundary_kernel(const int* __restrict__ tgt,
                                                       uint32_t* __restrict__ mask) {
    int b = blockIdx.x >> 9;
    int y = blockIdx.x & 511;
    int x = threadIdx.x;
    const int* timg = tgt + (size_t)b * HW;
    int t = timg[y * IMG_W + x];
    bool diff = false;
    #pragma unroll
    for (int dy = -1; dy <= 1; dy++) {
        int yy = y + dy;
        if (yy < 0 || yy > IMG_H - 1) continue;
        const int* rowp = timg + yy * IMG_W;
        #pragma unroll
        for (int dx = -1; dx <= 1; dx++) {
            int xx = x + dx;
            if (xx < 0 || xx > IMG_W - 1) continue;
            diff |= (rowp[xx] != t);
        }
    }
    unsigned long long m = __ballot(diff);
    int lane = threadIdx.x & 63;
    size_t widx = (size_t)b * (HW / 32) + y * (IMG_W / 32) + (threadIdx.x >> 5);
    if (lane == 0)
        mask[widx] = (uint32_t)m;
    else if (lane == 32)
        mask[widx] = (uint32_t)(m >> 32);
}

// ---------------------------------------------------------------------------
// Kernel 2 (FUSED dist + ce): one block per 64x64 tile (1024 blocks, 256 thr).
// Phase A: 15 bit-parallel dilations in LDS -> dtile (verified R1-R5).
// Phase B: ONLINE-softmax CE, CLASS-OUTER: each thread holds running
//   (m, s, lt) for 4 pixels and streams planes c=0..7 one at a time
//   (pipelined 1 ahead, nontemporal). Device-wide the instantaneous HBM
//   address window is ~1-2 planes instead of 8 -> DRAM row locality.
// ---------------------------------------------------------------------------
__global__ __launch_bounds__(256) void distce_kernel(const float* __restrict__ in,
                                                     const int* __restrict__ tgt,
                                                     const uint32_t* __restrict__ mask,
                                                     float* __restrict__ partials) {
    __shared__ uint32_t cur[RROWS][5];   // stride 5 words: conflict-light
    __shared__ uint8_t dtile[TILE][TILE];
    int b   = blockIdx.x >> 6;
    int tid = blockIdx.x & 63;
    int ty = tid >> 3, tx = tid & 7;
    int ry = ty * TILE;                  // tile top row in image
    int wx = tx * 2;                     // tile leftmost mask word
    const uint32_t* m = mask + (size_t)b * (HW / 32);
    int t = threadIdx.x;

    ((uint4*)dtile)[t] = make_uint4(0u, 0u, 0u, 0u);

    #pragma unroll
    for (int k = 0; k < 2; k++) {
        int task = t + 256 * k;
        if (task < NTASK) {
            int r = task >> 2, w = task & 3;
            int g  = ry - HALO + r;
            int gw = wx - 1 + w;
            uint32_t v = 0u;
            if ((unsigned)g < IMG_H && (unsigned)gw < 16u) v = m[g * 16 + gw];
            cur[r][w] = v;
        }
    }
    __syncthreads();

    int r0 = t >> 2, w0 = t & 3;
    int r1 = (t + 256) >> 2, w1 = t & 3;
    bool has1 = (t + 256) < NTASK;
    for (int it = 1; it <= 15; it++) {
        uint32_t nw0 = 0u, nw1 = 0u, old0, old1 = 0u;
        old0 = cur[r0][w0];
        #pragma unroll
        for (int dr = -1; dr <= 1; dr++) {
            int rr = r0 + dr;
            if ((unsigned)rr >= (unsigned)RROWS) continue;
            uint32_t v   = cur[rr][w0];
            uint32_t lft = (w0 > 0) ? cur[rr][w0 - 1] : 0u;
            uint32_t rgt = (w0 < 3) ? cur[rr][w0 + 1] : 0u;
            nw0 |= v | (v << 1) | (v >> 1) | (lft >> 31) | (rgt << 31);
        }
        if (has1) {
            old1 = cur[r1][w1];
            #pragma unroll
            for (int dr = -1; dr <= 1; dr++) {
                int rr = r1 + dr;
                if ((unsigned)rr >= (unsigned)RROWS) continue;
                uint32_t v   = cur[rr][w1];
                uint32_t lft = (w1 > 0) ? cur[rr][w1 - 1] : 0u;
                uint32_t rgt = (w1 < 3) ? cur[rr][w1 + 1] : 0u;
                nw1 |= v | (v << 1) | (v >> 1) | (lft >> 31) | (rgt << 31);
            }
        }
        __syncthreads();
        cur[r0][w0] = nw0;
        if ((w0 == 1 || w0 == 2) && r0 >= HALO && r0 < HALO + TILE) {
            uint32_t nb = nw0 & ~old0;
            while (nb) { int bit = __ffs(nb) - 1; nb &= nb - 1;
                         dtile[r0 - HALO][(w0 - 1) * 32 + bit] = (uint8_t)it; }
        }
        if (has1) {
            cur[r1][w1] = nw1;
            if ((w1 == 1 || w1 == 2) && r1 >= HALO && r1 < HALO + TILE) {
                uint32_t nb = nw1 & ~old1;
                while (nb) { int bit = __ffs(nb) - 1; nb &= nb - 1;
                             dtile[r1 - HALO][(w1 - 1) * 32 + bit] = (uint8_t)it; }
            }
        }
        __syncthreads();
    }

    // Phase B: class-outer online-softmax CE, 16 px/thread in 4 quads.
    float partial = 0.0f;
    const float* inb  = in  + (size_t)b * NC * HW;
    const int*   tgtb = tgt + (size_t)b * HW;
    #pragma unroll
    for (int g = 0; g < 4; g++) {
        int q = t + 256 * g;
        int row = q >> 4, quad = q & 15;
        int off = (ry + row) * IMG_W + tx * TILE + quad * 4;
        const float* base = inb + off;
        int4 t4 = *(const int4*)(tgtb + off);
        int tv[4] = {t4.x, t4.y, t4.z, t4.w};
        uint32_t d4 = *(const uint32_t*)&dtile[row][quad * 4];

        f4 v0  = __builtin_nontemporal_load((const f4*)base);
        f4 nxt = __builtin_nontemporal_load((const f4*)(base + HW));
        float m_[4], s_[4], lt_[4];
        #pragma unroll
        for (int j = 0; j < 4; j++) { m_[j] = v0[j]; s_[j] = 1.0f; lt_[j] = v0[j]; }

        #pragma unroll
        for (int c = 1; c < NC; c++) {
            f4 cv = nxt;
            if (c < NC - 1)
                nxt = __builtin_nontemporal_load((const f4*)(base + (size_t)(c + 1) * HW));
            #pragma unroll
            for (int j = 0; j < 4; j++) {
                float v = cv[j];
                float mn = fmaxf(m_[j], v);
                s_[j] = s_[j] * __expf(m_[j] - mn) + __expf(v - mn);
                m_[j] = mn;
                lt_[j] = (tv[j] == c) ? v : lt_[j];
            }
        }
        #pragma unroll
        for (int j = 0; j < 4; j++) {
            float lse = m_[j] + __logf(s_[j]);
            float ce = lse - lt_[j];
            float d = (float)((d4 >> (8 * j)) & 0xffu);
            partial += __expf(d * -0.2f) * ce;
        }
    }
    #pragma unroll
    for (int off = 32; off > 0; off >>= 1) partial += __shfl_down(partial, off);
    __shared__ float wsums[4];
    int lane = t & 63;
    int wid = t >> 6;
    if (lane == 0) wsums[wid] = partial;
    __syncthreads();
    if (t == 0)
        partials[blockIdx.x] = wsums[0] + wsums[1] + wsums[2] + wsums[3];
}

// ---------------------------------------------------------------------------
// Kernel 3: deterministic tree-reduce of 1024 partials -> mean. One block.
// ---------------------------------------------------------------------------
__global__ __launch_bounds__(256) void reduce_kernel(const float* __restrict__ partials,
                                                     float* __restrict__ out) {
    double s = 0.0;
    #pragma unroll
    for (int i = 0; i < NBLK / 256; i++)
        s += (double)partials[threadIdx.x + 256 * i];
    #pragma unroll
    for (int off = 32; off > 0; off >>= 1) s += __shfl_down(s, off);
    __shared__ double wsums[4];
    int lane = threadIdx.x & 63;
    int wid = threadIdx.x >> 6;
    if (lane == 0) wsums[wid] = s;
    __syncthreads();
    if (threadIdx.x == 0) {
        double tot = wsums[0] + wsums[1] + wsums[2] + wsums[3];
        out[0] = (float)(tot * (1.0 / (double)((size_t)NB * HW)));
    }
}

extern "C" void kernel_launch(void* const* d_in, const int* in_sizes, int n_in,
                              void* d_out, int out_size, void* d_ws, size_t ws_size,
                              hipStream_t stream) {
    const float* in  = (const float*)d_in[0];
    const int*   tgt = (const int*)d_in[1];
    float* out = (float*)d_out;

    char* ws = (char*)d_ws;
    uint32_t* mask     = (uint32_t*)(ws + 256);                  // 512 KB
    float*    partials = (float*)(ws + 256 + (size_t)NB * (HW / 32) * 4); // 4 KB

    boundary_kernel<<<NB * IMG_H, IMG_W, 0, stream>>>(tgt, mask);
    distce_kernel<<<NBLK, 256, 0, stream>>>(in, tgt, mask, partials);
    reduce_kernel<<<1, 256, 0, stream>>>(partials, out);
}

// Round 7
// 42.878 us; speedup vs baseline: 1.5586x; 1.5586x over previous
//
#include <hip/hip_runtime.h>
#include <stdint.h>

#define IMG_H 512
#define IMG_W 512
#define NB 16
#define NC 8
#define HW (IMG_H * IMG_W)

#define TILE 64
#define HALO 15
#define CROWS (TILE + 2 * HALO)       // 94 dilation rows (rel -15..78)
#define TROWS (CROWS + 2)             // 96 target rows  (rel -16..79)
#define TCOLS 96                      // target cols     (rel -16..79)
#define TSTRIDE 100                   // LDS row stride bytes (25 words, odd)
#define NTASK (CROWS * 3)             // 282 (row, word) tasks, 3 words/row
#define NBLK (NB * 64)

typedef float f4 __attribute__((ext_vector_type(4)));

// ---------------------------------------------------------------------------
// FULLY FUSED kernel: boundary + distance transform + weighted CE per tile.
// One block per 64x64 tile (1024 blocks, 256 threads).
//  P0: clamp-load 96x96 target patch -> LDS bytes (targets are L2/L3-hot;
//      clamp-padding duplicates valid compares -> boundary stays exact).
//  P1: boundary bits, word-parallel: 3 byte-shifted streams per row, XOR+OR
//      accumulate, per-byte nonzero -> 4 bits packed via multiply trick.
//      Words cover rel cols -16..79; bits at rel +-16 edges may be stale but
//      are >=16 Chebyshev from the inner tile -> unreachable in 15 iters.
//  P2: 15 bit-parallel dilations (verified R1-R6); new bits -> dtile[r][c].
//  P3: CE: logits streamed from global (8 planes, float4), targets read from
//      the LDS patch, dist from dtile. Block partial -> partials[] (no atomics).
// ---------------------------------------------------------------------------
__global__ __launch_bounds__(256) void distce_kernel(const float* __restrict__ in,
                                                     const int* __restrict__ tgt,
                                                     float* __restrict__ partials) {
    __shared__ uint8_t  tg[TROWS][TSTRIDE];   // 9600 B
    __shared__ uint32_t cur[CROWS][5];        // 1880 B (stride 5: conflict-light)
    __shared__ uint8_t  dtile[TILE][TILE];    // 4096 B
    int b   = blockIdx.x >> 6;
    int tid = blockIdx.x & 63;
    int ty = tid >> 3, tx = tid & 7;
    int ry = ty * TILE, rx = tx * TILE;
    int t = threadIdx.x;
    const int* tgtb = tgt + (size_t)b * HW;

    ((uint4*)dtile)[t] = make_uint4(0u, 0u, 0u, 0u);

    // ---- P0: clamp-load 96x96 target patch (9216 = 36*256 elements) ----
    #pragma unroll
    for (int k = 0; k < 36; k++) {
        int tau = t + 256 * k;
        int r = tau / TCOLS, c = tau % TCOLS;
        int gy = ry - 16 + r; gy = min(max(gy, 0), IMG_H - 1);
        int gx = rx - 16 + c; gx = min(max(gx, 0), IMG_W - 1);
        tg[r][c] = (uint8_t)tgtb[gy * IMG_W + gx];
    }
    __syncthreads();

    // ---- P1: boundary bit words. word w bit i <-> rel col 32w+i-16 ----
    for (int task = t; task < NTASK; task += 256) {
        int r = task / 3, w = task % 3;   // cur row r = rel row r-15
        int rr = r + 1;                   // tg row of the center row
        int gy = ry - 15 + r;
        uint32_t word = 0u;
        if (gy >= 0 && gy < IMG_H) {
            uint32_t Wc[10], Wa[10], Wb[10];
            const uint32_t* pc = (const uint32_t*)&tg[rr][0];
            const uint32_t* pa = (const uint32_t*)&tg[rr - 1][0];
            const uint32_t* pb = (const uint32_t*)&tg[rr + 1][0];
            #pragma unroll
            for (int k = 0; k < 10; k++) {
                int idx = 8 * w - 1 + k;
                idx = min(max(idx, 0), 23);   // row = 24 words; edge bits are dead
                Wc[k] = pc[idx]; Wa[k] = pa[idx]; Wb[k] = pb[idx];
            }
            #pragma unroll
            for (int i = 0; i < 8; i++) {
                uint32_t T = Wc[i + 1];
                uint32_t a;
                uint32_t L = (Wc[i + 1] << 8) | (Wc[i] >> 24);
                uint32_t R = (Wc[i + 1] >> 8) | (Wc[i + 2] << 24);
                a  = (T ^ L) | (T ^ R);
                uint32_t C2 = Wa[i + 1];
                uint32_t L2 = (Wa[i + 1] << 8) | (Wa[i] >> 24);
                uint32_t R2 = (Wa[i + 1] >> 8) | (Wa[i + 2] << 24);
                a |= (T ^ C2) | (T ^ L2) | (T ^ R2);
                uint32_t C3 = Wb[i + 1];
                uint32_t L3 = (Wb[i + 1] << 8) | (Wb[i] >> 24);
                uint32_t R3 = (Wb[i + 1] >> 8) | (Wb[i + 2] << 24);
                a |= (T ^ C3) | (T ^ L3) | (T ^ R3);
                uint32_t t1  = (a & 0x7F7F7F7Fu) + 0x7F7F7F7Fu;
                uint32_t nzb = ((t1 | a) & 0x80808080u) >> 7;      // bits 0,8,16,24
                word |= (((nzb * 0x01020408u) >> 24) & 0xFu) << (4 * i);
            }
            if (tx == 0 && w == 0) word &= 0xFFFF0000u;   // gx<0 not in image
            if (tx == 7 && w == 2) word &= 0x0000FFFFu;   // gx>=512 not in image
        }
        cur[r][w] = word;
    }
    __syncthreads();

    // ---- P2: 15 bit-parallel dilations; new bits -> dtile ----
    int r0 = t / 3, w0 = t % 3;
    int t1i = t + 256;
    int r1 = t1i / 3, w1 = t1i % 3;
    bool has1 = t1i < NTASK;
    const uint32_t livemask[3] = {0xFFFF0000u, 0xFFFFFFFFu, 0x0000FFFFu};
    for (int it = 1; it <= 15; it++) {
        uint32_t n0 = 0u, n1 = 0u, o0, o1 = 0u;
        o0 = cur[r0][w0];
        #pragma unroll
        for (int dr = -1; dr <= 1; dr++) {
            int rr2 = r0 + dr;
            if ((unsigned)rr2 >= (unsigned)CROWS) continue;
            uint32_t v  = cur[rr2][w0];
            uint32_t lf = (w0 > 0) ? cur[rr2][w0 - 1] : 0u;
            uint32_t rg = (w0 < 2) ? cur[rr2][w0 + 1] : 0u;
            n0 |= v | (v << 1) | (v >> 1) | (lf >> 31) | (rg << 31);
        }
        if (has1) {
            o1 = cur[r1][w1];
            #pragma unroll
            for (int dr = -1; dr <= 1; dr++) {
                int rr2 = r1 + dr;
                if ((unsigned)rr2 >= (unsigned)CROWS) continue;
                uint32_t v  = cur[rr2][w1];
                uint32_t lf = (w1 > 0) ? cur[rr2][w1 - 1] : 0u;
                uint32_t rg = (w1 < 2) ? cur[rr2][w1 + 1] : 0u;
                n1 |= v | (v << 1) | (v >> 1) | (lf >> 31) | (rg << 31);
            }
        }
        __syncthreads();
        cur[r0][w0] = n0;
        if (r0 >= HALO && r0 < HALO + TILE) {
            uint32_t nb = (n0 & ~o0) & livemask[w0];
            while (nb) { int bit = __ffs(nb) - 1; nb &= nb - 1;
                         dtile[r0 - HALO][w0 * 32 + bit - 16] = (uint8_t)it; }
        }
        if (has1) {
            cur[r1][w1] = n1;
            if (r1 >= HALO && r1 < HALO + TILE) {
                uint32_t nb = (n1 & ~o1) & livemask[w1];
                while (nb) { int bit = __ffs(nb) - 1; nb &= nb - 1;
                             dtile[r1 - HALO][w1 * 32 + bit - 16] = (uint8_t)it; }
            }
        }
        __syncthreads();
    }

    // ---- P3: CE over the tile, 16 px/thread; targets from LDS patch ----
    float partial = 0.0f;
    const float* inb = in + (size_t)b * NC * HW;
    #pragma unroll
    for (int g = 0; g < 4; g++) {
        int q = t + 256 * g;
        int row = q >> 4, quad = q & 15;
        const float* base = inb + (ry + row) * IMG_W + rx + quad * 4;
        float v[NC][4];
        #pragma unroll
        for (int c = 0; c < NC; c++) {
            f4 f = *(const f4*)(base + (size_t)c * HW);
            v[c][0] = f.x; v[c][1] = f.y; v[c][2] = f.z; v[c][3] = f.w;
        }
        uint32_t tw = ((const uint32_t*)&tg[16 + row][0])[4 + quad];
        uint32_t d4 = *(const uint32_t*)&dtile[row][quad * 4];
        #pragma unroll
        for (int j = 0; j < 4; j++) {
            float mx = v[0][j];
            #pragma unroll
            for (int c = 1; c < NC; c++) mx = fmaxf(mx, v[c][j]);
            float s = 0.0f;
            #pragma unroll
            for (int c = 0; c < NC; c++) s += __expf(v[c][j] - mx);
            float lse = mx + __logf(s);
            int tc = (int)((tw >> (8 * j)) & 0xFFu);
            float lt = v[0][j];
            #pragma unroll
            for (int c = 1; c < NC; c++) lt = (tc == c) ? v[c][j] : lt;
            float ce = lse - lt;
            float d = (float)((d4 >> (8 * j)) & 0xFFu);
            partial += __expf(d * -0.2f) * ce;
        }
    }
    #pragma unroll
    for (int off = 32; off > 0; off >>= 1) partial += __shfl_down(partial, off);
    __shared__ float wsums[4];
    int lane = t & 63;
    int wid = t >> 6;
    if (lane == 0) wsums[wid] = partial;
    __syncthreads();
    if (t == 0)
        partials[blockIdx.x] = wsums[0] + wsums[1] + wsums[2] + wsums[3];
}

// ---------------------------------------------------------------------------
// Deterministic tree-reduce of 1024 partials -> mean. One block.
// ---------------------------------------------------------------------------
__global__ __launch_bounds__(256) void reduce_kernel(const float* __restrict__ partials,
                                                     float* __restrict__ out) {
    double s = 0.0;
    #pragma unroll
    for (int i = 0; i < NBLK / 256; i++)
        s += (double)partials[threadIdx.x + 256 * i];
    #pragma unroll
    for (int off = 32; off > 0; off >>= 1) s += __shfl_down(s, off);
    __shared__ double wsums[4];
    int lane = threadIdx.x & 63;
    int wid = threadIdx.x >> 6;
    if (lane == 0) wsums[wid] = s;
    __syncthreads();
    if (threadIdx.x == 0) {
        double tot = wsums[0] + wsums[1] + wsums[2] + wsums[3];
        out[0] = (float)(tot * (1.0 / (double)((size_t)NB * HW)));
    }
}

extern "C" void kernel_launch(void* const* d_in, const int* in_sizes, int n_in,
                              void* d_out, int out_size, void* d_ws, size_t ws_size,
                              hipStream_t stream) {
    const float* in  = (const float*)d_in[0];
    const int*   tgt = (const int*)d_in[1];
    float* out = (float*)d_out;

    float* partials = (float*)((char*)d_ws + 256);   // 4 KB

    distce_kernel<<<NBLK, 256, 0, stream>>>(in, tgt, partials);
    reduce_kernel<<<1, 256, 0, stream>>>(partials, out);
}